// Round 2
// baseline (252.869 us; speedup 1.0000x reference)
//
#include <hip/hip_runtime.h>

#define DIM 64
#define H1  128
#define H2  16
#define NC  4
#define VCH 5
#define IMG 224
#define PP  (IMG * IMG)   // 50176
#define BB  32

// ---------------------------------------------------------------------------
// Kernel A: tiny MLP + LayerNorm for q (32 rows) and k (128 rows).
// One block per row, 128 threads. Results -> ws:
//   ws[0 .. 512)          q16[b][j]
//   ws[512 .. 2560)       k16[b][c][j]
// ---------------------------------------------------------------------------
__global__ __launch_bounds__(128) void mlp_kernel(
    const float* __restrict__ q, const float* __restrict__ k,
    const float* __restrict__ Wq1, const float* __restrict__ bq1,
    const float* __restrict__ Wq2, const float* __restrict__ bq2,
    const float* __restrict__ gq,  const float* __restrict__ betaq,
    const float* __restrict__ Wk1, const float* __restrict__ bk1,
    const float* __restrict__ Wk2, const float* __restrict__ bk2,
    const float* __restrict__ gk,  const float* __restrict__ betak,
    float* __restrict__ ws)
{
    __shared__ float xs[DIM];
    __shared__ float sh1[H1];
    __shared__ float sh2[H2];

    const int row = blockIdx.x;     // 0..159
    const int tid = threadIdx.x;    // 0..127
    const bool isq = (row < BB);

    const float *W1, *b1, *W2, *b2, *g, *beta;
    int b, c;
    if (isq) {
        b = row; c = 0;
        W1 = Wq1; b1 = bq1; W2 = Wq2; b2 = bq2; g = gq; beta = betaq;
    } else {
        const int idx = row - BB;
        b = idx >> 2; c = idx & 3;
        W1 = Wk1; b1 = bk1; W2 = Wk2; b2 = bk2; g = gk; beta = betak;
    }

    if (tid < DIM) {
        // q: (B,DIM,1) flat b*64+d ; k: (B,DIM,1,C) flat (b*64+d)*4+c
        xs[tid] = isq ? q[b * DIM + tid] : k[(b * DIM + tid) * NC + c];
    }
    __syncthreads();

    // h1[tid] = leaky_relu( b1[tid] + sum_d x[d] * W1[d][tid] )
    float acc = b1[tid];
#pragma unroll 8
    for (int d = 0; d < DIM; ++d)
        acc = fmaf(xs[d], W1[d * H1 + tid], acc);
    sh1[tid] = (acc > 0.0f) ? acc : 0.1f * acc;
    __syncthreads();

    if (tid < H2) {
        float a2 = b2[tid];
#pragma unroll 8
        for (int i = 0; i < H1; ++i)
            a2 = fmaf(sh1[i], W2[i * H2 + tid], a2);
        sh2[tid] = a2;
    }
    __syncthreads();

    if (tid < H2) {
        float mu = 0.0f;
#pragma unroll
        for (int j = 0; j < H2; ++j) mu += sh2[j];
        mu *= (1.0f / H2);
        float var = 0.0f;
#pragma unroll
        for (int j = 0; j < H2; ++j) { float d0 = sh2[j] - mu; var += d0 * d0; }
        var *= (1.0f / H2);
        const float y = (sh2[tid] - mu) * rsqrtf(var + 1e-5f) * g[tid] + beta[tid];
        float* out = isq ? (ws + b * H2) : (ws + BB * H2 + (b * NC + c) * H2);
        out[tid] = y;
    }
}

// ---------------------------------------------------------------------------
// Kernel B: per-pixel fusion. 6272 blocks x 256 threads; each block covers
// 256 consecutive pixels of one batch b (P = 196 * 256 exactly).
// Threads 0..3 compute the 4-way softmax for this b from ws (L2-cached).
// Each thread: 1 float4 mask load, 5 float4 v loads (nontemporal), 9 stores
// (nontemporal — outputs never re-read).
// ---------------------------------------------------------------------------
__global__ __launch_bounds__(256) void fuse_kernel(
    const float* __restrict__ v, const float* __restrict__ mask,
    const int* __restrict__ md, const float* __restrict__ ws,
    float* __restrict__ out_fused, float* __restrict__ out_attn)
{
    __shared__ float l_s[NC];
    __shared__ float att_s[NC];

    const int bid = blockIdx.x;
    const int b   = bid / (PP / 256);                 // 196 blocks per batch
    const int p   = (bid % (PP / 256)) * 256 + threadIdx.x;

    if (threadIdx.x < NC) {
        const int c = threadIdx.x;
        const float* q16 = ws + b * H2;
        const float* k16 = ws + BB * H2 + (b * NC + c) * H2;
        float dot = 0.0f;
#pragma unroll
        for (int j = 0; j < H2; ++j) dot = fmaf(q16[j], k16[j], dot);
        // scale = DIM^-0.5 = 0.125 exact; modality dropout; / TEMPERATURE
        const float logit = dot * 0.125f - (float)md[b * NC + c] * 1.0e5f;
        l_s[c] = logit * 0.1f;
    }
    __syncthreads();
    if (threadIdx.x < NC) {
        const int c = threadIdx.x;
        const float m = fmaxf(fmaxf(l_s[0], l_s[1]), fmaxf(l_s[2], l_s[3]));
        const float e = __expf(l_s[c] - m);
        const float s = __expf(l_s[0] - m) + __expf(l_s[1] - m) +
                        __expf(l_s[2] - m) + __expf(l_s[3] - m);
        att_s[c] = e / s;
    }
    __syncthreads();

    // mask: (B,1,IMG,IMG,C) flat (b*P+p)*4
    const float4 mk = *reinterpret_cast<const float4*>(mask + (size_t)(b * PP + p) * NC);
    float a0 = att_s[0] * mk.x;
    float a1 = att_s[1] * mk.y;
    float a2 = att_s[2] * mk.z;
    float a3 = att_s[3] * mk.w;
    const float inv = 1.0f / (a0 + a1 + a2 + a3 + 1e-8f);
    a0 *= inv; a1 *= inv; a2 *= inv; a3 *= inv;

    // attention out: (B,C,IMG,IMG)
    const size_t ab = (size_t)b * NC * PP + p;
    __builtin_nontemporal_store(a0, out_attn + ab);
    __builtin_nontemporal_store(a1, out_attn + ab + PP);
    __builtin_nontemporal_store(a2, out_attn + ab + 2 * PP);
    __builtin_nontemporal_store(a3, out_attn + ab + 3 * PP);

    // fused out: (B,V_CH,IMG,IMG); v: (B,V_CH,P,C) flat ((b*5+vc)*P+p)*4
    const size_t vb = (size_t)b * VCH * PP + p;
#pragma unroll
    for (int vc = 0; vc < VCH; ++vc) {
        const float* vp = v + (vb + (size_t)vc * PP) * NC;
        float vx = __builtin_nontemporal_load(vp);
        float vy = __builtin_nontemporal_load(vp + 1);
        float vz = __builtin_nontemporal_load(vp + 2);
        float vw = __builtin_nontemporal_load(vp + 3);
        const float f = a0 * vx + a1 * vy + a2 * vz + a3 * vw;
        __builtin_nontemporal_store(f, out_fused + vb + (size_t)vc * PP);
    }
}

extern "C" void kernel_launch(void* const* d_in, const int* in_sizes, int n_in,
                              void* d_out, int out_size, void* d_ws, size_t ws_size,
                              hipStream_t stream) {
    const float* q     = (const float*)d_in[0];
    const float* k     = (const float*)d_in[1];
    const float* v     = (const float*)d_in[2];
    const float* mask  = (const float*)d_in[3];
    const int*   md    = (const int*)  d_in[4];
    const float* Wq1   = (const float*)d_in[5];
    const float* bq1   = (const float*)d_in[6];
    const float* Wq2   = (const float*)d_in[7];
    const float* bq2   = (const float*)d_in[8];
    const float* gq    = (const float*)d_in[9];
    const float* betaq = (const float*)d_in[10];
    const float* Wk1   = (const float*)d_in[11];
    const float* bk1   = (const float*)d_in[12];
    const float* Wk2   = (const float*)d_in[13];
    const float* bk2   = (const float*)d_in[14];
    const float* gk    = (const float*)d_in[15];
    const float* betak = (const float*)d_in[16];

    float* ws        = (float*)d_ws;
    float* out_fused = (float*)d_out;                       // B*V_CH*P floats
    float* out_attn  = out_fused + (size_t)BB * VCH * PP;   // B*C*P floats

    hipLaunchKernelGGL(mlp_kernel, dim3(BB + BB * NC), dim3(128), 0, stream,
                       q, k, Wq1, bq1, Wq2, bq2, gq, betaq,
                       Wk1, bk1, Wk2, bk2, gk, betak, ws);

    hipLaunchKernelGGL(fuse_kernel, dim3(BB * (PP / 256)), dim3(256), 0, stream,
                       v, mask, md, ws, out_fused, out_attn);
}

// Round 3
// 247.449 us; speedup vs baseline: 1.0219x; 1.0219x over previous
//
#include <hip/hip_runtime.h>

#define DIM 64
#define H1  128
#define H2  16
#define NC  4
#define VCH 5
#define IMG 224
#define PP  (IMG * IMG)   // 50176
#define BB  32

typedef float f4 __attribute__((ext_vector_type(4)));

// ws layout (floats):
//   [0, 512)      q16[b][j]
//   [512, 2560)   k16[b][c][j]
//   [2560, 2688)  att[b][c]   (softmax weights, pre-divided by nothing else)

// ---------------------------------------------------------------------------
// Kernel A: tiny MLP + LayerNorm for q (32 rows) and k (128 rows).
// One block per row, 128 threads.
// ---------------------------------------------------------------------------
__global__ __launch_bounds__(128) void mlp_kernel(
    const float* __restrict__ q, const float* __restrict__ k,
    const float* __restrict__ Wq1, const float* __restrict__ bq1,
    const float* __restrict__ Wq2, const float* __restrict__ bq2,
    const float* __restrict__ gq,  const float* __restrict__ betaq,
    const float* __restrict__ Wk1, const float* __restrict__ bk1,
    const float* __restrict__ Wk2, const float* __restrict__ bk2,
    const float* __restrict__ gk,  const float* __restrict__ betak,
    float* __restrict__ ws)
{
    __shared__ float xs[DIM];
    __shared__ float sh1[H1];
    __shared__ float sh2[H2];

    const int row = blockIdx.x;     // 0..159
    const int tid = threadIdx.x;    // 0..127
    const bool isq = (row < BB);

    const float *W1, *b1, *W2, *b2, *g, *beta;
    int b, c;
    if (isq) {
        b = row; c = 0;
        W1 = Wq1; b1 = bq1; W2 = Wq2; b2 = bq2; g = gq; beta = betaq;
    } else {
        const int idx = row - BB;
        b = idx >> 2; c = idx & 3;
        W1 = Wk1; b1 = bk1; W2 = Wk2; b2 = bk2; g = gk; beta = betak;
    }

    if (tid < DIM) {
        // q: (B,DIM,1) flat b*64+d ; k: (B,DIM,1,C) flat (b*64+d)*4+c
        xs[tid] = isq ? q[b * DIM + tid] : k[(b * DIM + tid) * NC + c];
    }
    __syncthreads();

    float acc = b1[tid];
#pragma unroll 8
    for (int d = 0; d < DIM; ++d)
        acc = fmaf(xs[d], W1[d * H1 + tid], acc);
    sh1[tid] = (acc > 0.0f) ? acc : 0.1f * acc;
    __syncthreads();

    if (tid < H2) {
        float a2 = b2[tid];
#pragma unroll 8
        for (int i = 0; i < H1; ++i)
            a2 = fmaf(sh1[i], W2[i * H2 + tid], a2);
        sh2[tid] = a2;
    }
    __syncthreads();

    if (tid < H2) {
        float mu = 0.0f;
#pragma unroll
        for (int j = 0; j < H2; ++j) mu += sh2[j];
        mu *= (1.0f / H2);
        float var = 0.0f;
#pragma unroll
        for (int j = 0; j < H2; ++j) { float d0 = sh2[j] - mu; var += d0 * d0; }
        var *= (1.0f / H2);
        const float y = (sh2[tid] - mu) * rsqrtf(var + 1e-5f) * g[tid] + beta[tid];
        float* out = isq ? (ws + b * H2) : (ws + BB * H2 + (b * NC + c) * H2);
        out[tid] = y;
    }
}

// ---------------------------------------------------------------------------
// Kernel B: logits + softmax for all (b,c). One block, 128 threads,
// lane tid = b*4+c; 4-lane-group shuffle softmax. Writes att to ws+2560.
// ---------------------------------------------------------------------------
__global__ __launch_bounds__(128) void att_kernel(
    const int* __restrict__ md, float* __restrict__ ws)
{
    const int tid = threadIdx.x;    // 0..127
    const int b = tid >> 2, c = tid & 3;
    const float* q16 = ws + b * H2;
    const float* k16 = ws + BB * H2 + tid * H2;
    float dot = 0.0f;
#pragma unroll
    for (int j = 0; j < H2; ++j) dot = fmaf(q16[j], k16[j], dot);
    // scale = DIM^-0.5 = 0.125; modality dropout; / TEMPERATURE(10)
    float l = (dot * 0.125f - (float)md[tid] * 1.0e5f) * 0.1f;
    // max over the 4-lane contrast group
    float m = l;
    m = fmaxf(m, __shfl_xor(m, 1, 64));
    m = fmaxf(m, __shfl_xor(m, 2, 64));
    float e = __expf(l - m);
    float s = e;
    s += __shfl_xor(s, 1, 64);
    s += __shfl_xor(s, 2, 64);
    ws[BB * H2 + BB * NC * H2 + tid] = e / s;
}

// ---------------------------------------------------------------------------
// Kernel C: per-pixel fusion. 6272 blocks x 256 threads; block covers 256
// consecutive pixels of one batch b. No LDS, no barriers. Per thread:
// 1 dwordx4 mask load + 5 dwordx4 v loads (nontemporal) + 9 nt stores.
// ---------------------------------------------------------------------------
__global__ __launch_bounds__(256) void fuse_kernel(
    const float* __restrict__ v, const float* __restrict__ mask,
    const float* __restrict__ ws,
    float* __restrict__ out_fused, float* __restrict__ out_attn)
{
    const int bid = blockIdx.x;
    const int b   = bid / (PP / 256);                 // 196 blocks per batch
    const int p   = (bid % (PP / 256)) * 256 + threadIdx.x;

    // wave-uniform attention weights (L2-resident broadcast)
    const float* att = ws + BB * H2 + BB * NC * H2 + b * NC;
    const float t0 = att[0], t1 = att[1], t2 = att[2], t3 = att[3];

    // mask: (B,1,IMG,IMG,C) flat (b*P+p)*4
    const f4 mk = __builtin_nontemporal_load(
        reinterpret_cast<const f4*>(mask + (size_t)(b * PP + p) * NC));
    float a0 = t0 * mk.x;
    float a1 = t1 * mk.y;
    float a2 = t2 * mk.z;
    float a3 = t3 * mk.w;
    const float inv = 1.0f / (a0 + a1 + a2 + a3 + 1e-8f);
    a0 *= inv; a1 *= inv; a2 *= inv; a3 *= inv;

    // attention out: (B,C,IMG,IMG)
    const size_t ab = (size_t)b * NC * PP + p;
    __builtin_nontemporal_store(a0, out_attn + ab);
    __builtin_nontemporal_store(a1, out_attn + ab + PP);
    __builtin_nontemporal_store(a2, out_attn + ab + 2 * PP);
    __builtin_nontemporal_store(a3, out_attn + ab + 3 * PP);

    // fused out: (B,V_CH,IMG,IMG); v: (B,V_CH,P,C) flat ((b*5+vc)*P+p)*4
    const size_t vb = (size_t)b * VCH * PP + p;
#pragma unroll
    for (int vc = 0; vc < VCH; ++vc) {
        const f4 vv = __builtin_nontemporal_load(
            reinterpret_cast<const f4*>(v + (vb + (size_t)vc * PP) * NC));
        const float f = a0 * vv.x + a1 * vv.y + a2 * vv.z + a3 * vv.w;
        __builtin_nontemporal_store(f, out_fused + vb + (size_t)vc * PP);
    }
}

extern "C" void kernel_launch(void* const* d_in, const int* in_sizes, int n_in,
                              void* d_out, int out_size, void* d_ws, size_t ws_size,
                              hipStream_t stream) {
    const float* q     = (const float*)d_in[0];
    const float* k     = (const float*)d_in[1];
    const float* v     = (const float*)d_in[2];
    const float* mask  = (const float*)d_in[3];
    const int*   md    = (const int*)  d_in[4];
    const float* Wq1   = (const float*)d_in[5];
    const float* bq1   = (const float*)d_in[6];
    const float* Wq2   = (const float*)d_in[7];
    const float* bq2   = (const float*)d_in[8];
    const float* gq    = (const float*)d_in[9];
    const float* betaq = (const float*)d_in[10];
    const float* Wk1   = (const float*)d_in[11];
    const float* bk1   = (const float*)d_in[12];
    const float* Wk2   = (const float*)d_in[13];
    const float* bk2   = (const float*)d_in[14];
    const float* gk    = (const float*)d_in[15];
    const float* betak = (const float*)d_in[16];

    float* ws        = (float*)d_ws;
    float* out_fused = (float*)d_out;                       // B*V_CH*P floats
    float* out_attn  = out_fused + (size_t)BB * VCH * PP;   // B*C*P floats

    hipLaunchKernelGGL(mlp_kernel, dim3(BB + BB * NC), dim3(128), 0, stream,
                       q, k, Wq1, bq1, Wq2, bq2, gq, betaq,
                       Wk1, bk1, Wk2, bk2, gk, betak, ws);

    hipLaunchKernelGGL(att_kernel, dim3(1), dim3(128), 0, stream, md, ws);

    hipLaunchKernelGGL(fuse_kernel, dim3(BB * (PP / 256)), dim3(256), 0, stream,
                       v, mask, ws, out_fused, out_attn);
}